// Round 3
// baseline (88.923 us; speedup 1.0000x reference)
//
#include <hip/hip_runtime.h>
#include <hip/hip_bf16.h>

typedef short short8 __attribute__((ext_vector_type(8)));
typedef float f32x4 __attribute__((ext_vector_type(4)));

#define INV_SQRT2F 0.70710678118654752440f

__device__ __forceinline__ unsigned short f2bf(float f) {
  union { float f; unsigned u; } v; v.f = f;
  unsigned u = v.u;
  unsigned r = (u + 0x7FFFu + ((u >> 16) & 1u)) >> 16;  // RNE
  return (unsigned short)r;
}

// ---------------------------------------------------------------------------
// Precompute: W'[e,:] = inverse Haar transform of W[e,:]  (since out = (W H) x),
// packed as bf16 in MFMA B-fragment layout:
//   flat bf16 index = ((nblk*8 + kk)*64 + lane)*8 + j
//   where e = nblk*16 + (lane&15), k = kk*32 + (lane>>4)*8 + j
// ---------------------------------------------------------------------------
__global__ void haar_pack(const float* __restrict__ W, unsigned short* __restrict__ Wp) {
  __shared__ float cbuf[4][256];
  __shared__ float buf0[4][256];
  __shared__ float buf1[4][256];
  const int tid = threadIdx.x;
  const int w = tid >> 6, l = tid & 63;
  const int e = blockIdx.x * 4 + w;
  const float* row = W + e * 256;
  for (int k = l; k < 256; k += 64) cbuf[w][k] = row[k];
  __syncthreads();
  if (l == 0) buf0[w][0] = cbuf[w][0];   // a = [cA_8]
  __syncthreads();
  float* A = buf0[w];
  float* Bv = buf1[w];
  int len = 1;
  // coeff layout: [cA_8(1), cD_8(1), cD_7(2), ..., cD_1(128)]; offset(cD_lev)=len
  for (int s = 0; s < 8; ++s) {
    for (int k = l; k < len; k += 64) {
      float av = A[k], dv = cbuf[w][len + k];
      Bv[2 * k]     = (av + dv) * INV_SQRT2F;   // even
      Bv[2 * k + 1] = (av - dv) * INV_SQRT2F;   // odd
    }
    __syncthreads();
    float* t = A; A = Bv; Bv = t;
    len <<= 1;
  }
  const int nblk = e >> 4, lr = e & 15;
  for (int k = l; k < 256; k += 64) {
    int kk = k >> 5, win = k & 31, lhi = win >> 3, j = win & 7;
    int lane = lhi * 16 + lr;
    Wp[(((nblk * 8 + kk) * 64 + lane) << 3) + j] = f2bf(A[k]);
  }
}

// ---------------------------------------------------------------------------
// GEMM: out[m, e] = sum_k x[m,k]*W'[e,k] + b[e]
// Persistent-B design: all of B (128 KB bf16, fragment layout) staged to LDS
// once per block; A streamed global->register fragments (fp32->bf16), no
// A-LDS, no barriers in the main loop. 512 thr = 8 waves = 2 wm x 4 wn;
// wave tile 128 x 64; block tile 256 rows x 256 cols. Grid 512.
// ---------------------------------------------------------------------------
__global__ __launch_bounds__(512, 2) void wemb_gemm(
    const float* __restrict__ x, const unsigned short* __restrict__ Wp,
    const float* __restrict__ bias, float* __restrict__ out) {
  __shared__ char blds[131072];
  const int tid = threadIdx.x;

  // ---- stage all of B: 128 KB, linear copy (conflict-free) ----
  {
    const ulonglong2* src = (const ulonglong2*)Wp;
    ulonglong2* dst = (ulonglong2*)blds;
#pragma unroll
    for (int i = 0; i < 16; ++i) dst[i * 512 + tid] = src[i * 512 + tid];
  }
  __syncthreads();

  const int w = tid >> 6, lane = tid & 63;
  const int wm = w >> 2, wn = w & 3;
  const int lr = lane & 15, lhi = lane >> 4;
  const long rowWave = (long)blockIdx.x * 256 + wm * 128;
  const float* xw = x + rowWave * 256;

  f32x4 acc[8][4];
#pragma unroll
  for (int m = 0; m < 8; ++m)
#pragma unroll
    for (int n = 0; n < 4; ++n) acc[m][n] = (f32x4){0.f, 0.f, 0.f, 0.f};

  float bv[4];
#pragma unroll
  for (int n = 0; n < 4; ++n) bv[n] = bias[wn * 64 + n * 16 + lr];

#pragma unroll
  for (int kk = 0; kk < 8; ++kk) {
    // A fragments for this kk: lane(lr,lhi) holds x[row, kk*32+lhi*8 .. +7]
    short8 a[8];
#pragma unroll
    for (int m = 0; m < 8; ++m) {
      const float* p = xw + (m * 16 + lr) * 256 + kk * 32 + lhi * 8;
      float4 lo = *(const float4*)p;
      float4 hi = *(const float4*)(p + 4);
      union { short8 s; __hip_bfloat16 h[8]; } u;
      u.h[0] = __float2bfloat16(lo.x); u.h[1] = __float2bfloat16(lo.y);
      u.h[2] = __float2bfloat16(lo.z); u.h[3] = __float2bfloat16(lo.w);
      u.h[4] = __float2bfloat16(hi.x); u.h[5] = __float2bfloat16(hi.y);
      u.h[6] = __float2bfloat16(hi.z); u.h[7] = __float2bfloat16(hi.w);
      a[m] = u.s;
    }
#pragma unroll
    for (int n = 0; n < 4; ++n) {
      short8 b = *(const short8*)(blds + ((((wn * 4 + n) * 8 + kk) * 64 + lane) << 4));
#pragma unroll
      for (int m = 0; m < 8; ++m)
        acc[m][n] = __builtin_amdgcn_mfma_f32_16x16x32_bf16(a[m], b, acc[m][n], 0, 0, 0);
    }
  }

  // ---- epilogue: bias + store (C/D: col=lane&15 -> e, row=(lane>>4)*4+r) ----
#pragma unroll
  for (int m = 0; m < 8; ++m) {
#pragma unroll
    for (int n = 0; n < 4; ++n) {
      int e = wn * 64 + n * 16 + lr;
      float* o = out + (rowWave + m * 16 + lhi * 4) * 256 + e;
#pragma unroll
      for (int r = 0; r < 4; ++r) o[r * 256] = acc[m][n][r] + bv[n];
    }
  }
}

extern "C" void kernel_launch(void* const* d_in, const int* in_sizes, int n_in,
                              void* d_out, int out_size, void* d_ws, size_t ws_size,
                              hipStream_t stream) {
  const float* x = (const float*)d_in[0];     // (16, 8192, 256) fp32
  const float* W = (const float*)d_in[1];     // (256, 256) fp32
  const float* b = (const float*)d_in[2];     // (256,) fp32
  float* out = (float*)d_out;                 // (16, 8192, 256) fp32
  unsigned short* Wp = (unsigned short*)d_ws; // 256*256 bf16 = 128 KB

  haar_pack<<<64, 256, 0, stream>>>(W, Wp);

  const int grid = (out_size / 256) / 256;    // 131072 rows / 256 per block = 512
  wemb_gemm<<<grid, 512, 0, stream>>>(x, Wp, b, out);
}

// Round 4
// 58.125 us; speedup vs baseline: 1.5299x; 1.5299x over previous
//
#include <hip/hip_runtime.h>
#include <hip/hip_bf16.h>

typedef short short8 __attribute__((ext_vector_type(8)));
typedef float f32x4 __attribute__((ext_vector_type(4)));

#define INV_SQRT2F 0.70710678118654752440f

__device__ __forceinline__ unsigned short f2bf(float f) {
  union { float f; unsigned u; } v; v.f = f;
  unsigned u = v.u;
  unsigned r = (u + 0x7FFFu + ((u >> 16) & 1u)) >> 16;  // RNE
  return (unsigned short)r;
}

// ---------------------------------------------------------------------------
// Precompute: W'[e,:] = inverse Haar transform of W[e,:]  (since out = (W H) x),
// packed as bf16 in MFMA B-fragment layout:
//   flat bf16 index = ((nblk*8 + kk)*64 + lane)*8 + j
//   where e = nblk*16 + (lane&15), k = kk*32 + (lane>>4)*8 + j
// ---------------------------------------------------------------------------
__global__ void haar_pack(const float* __restrict__ W, unsigned short* __restrict__ Wp) {
  __shared__ float cbuf[4][256];
  __shared__ float buf0[4][256];
  __shared__ float buf1[4][256];
  const int tid = threadIdx.x;
  const int w = tid >> 6, l = tid & 63;
  const int e = blockIdx.x * 4 + w;
  const float* row = W + e * 256;
  for (int k = l; k < 256; k += 64) cbuf[w][k] = row[k];
  __syncthreads();
  if (l == 0) buf0[w][0] = cbuf[w][0];   // a = [cA_8]
  __syncthreads();
  float* A = buf0[w];
  float* Bv = buf1[w];
  int len = 1;
  // coeff layout: [cA_8(1), cD_8(1), cD_7(2), ..., cD_1(128)]; offset(cD_lev)=len
  for (int s = 0; s < 8; ++s) {
    for (int k = l; k < len; k += 64) {
      float av = A[k], dv = cbuf[w][len + k];
      Bv[2 * k]     = (av + dv) * INV_SQRT2F;   // even
      Bv[2 * k + 1] = (av - dv) * INV_SQRT2F;   // odd
    }
    __syncthreads();
    float* t = A; A = Bv; Bv = t;
    len <<= 1;
  }
  const int nblk = e >> 4, lr = e & 15;
  for (int k = l; k < 256; k += 64) {
    int kk = k >> 5, win = k & 31, lhi = win >> 3, j = win & 7;
    int lane = lhi * 16 + lr;
    Wp[(((nblk * 8 + kk) * 64 + lane) << 3) + j] = f2bf(A[k]);
  }
}

// ---------------------------------------------------------------------------
// Persistent-block streaming GEMM: out[m,e] = sum_k x[m,k] W'[e,k] + b[e]
// - B (256x256 bf16, frag layout) staged in LDS once per block (128 KB).
// - Each block = 8 waves (2 wm x 4 wn), wave tile 16 rows x 64 cols.
// - Streams 16 consecutive 32-row tiles; next tile prefetched to regs while
//   MFMA runs from LDS (only vmcnt users are prefetch + stores -> true
//   async overlap), then cvt+ds_write between two barriers.
// - A tile: 32 rows x 512 B bf16, XOR-swizzled byte ^= (row&7)<<4.
// ---------------------------------------------------------------------------
#define NTILES 16
#define BM 32

__global__ __launch_bounds__(512, 2) void wemb_gemm(
    const float* __restrict__ x, const unsigned short* __restrict__ Wp,
    const float* __restrict__ bias, float* __restrict__ out) {
  __shared__ char bl[131072];   // B, fragment layout (linear copy of Wp)
  __shared__ char al[16384];    // A tile: 32 rows x 512 B, swizzled bf16
  const int tid = threadIdx.x;

  // ---- copy all of B into LDS (coalesced, conflict-free) ----
  {
    const ulonglong2* s = (const ulonglong2*)Wp;
    ulonglong2* d = (ulonglong2*)bl;
#pragma unroll
    for (int i = 0; i < 16; ++i) d[i * 512 + tid] = s[i * 512 + tid];
  }

  const int w = tid >> 6, lane = tid & 63;
  const int wm = w >> 2, wn = w & 3;      // 2 x 4 wave grid
  const int lr = lane & 15, lhi = lane >> 4;

  float bv[4];
#pragma unroll
  for (int n = 0; n < 4; ++n) bv[n] = bias[wn * 64 + n * 16 + lr];

  const long tile0 = (long)blockIdx.x * NTILES;

  // ---- prologue: stage tile 0 ----
  {
    const float4* src = (const float4*)(x + tile0 * (BM * 256));
#pragma unroll
    for (int i = 0; i < 4; ++i) {
      int f = i * 512 + tid;
      float4 v = src[f];
      int row = f >> 6, colb = (f & 63) * 8;
      ushort4 p; p.x = f2bf(v.x); p.y = f2bf(v.y); p.z = f2bf(v.z); p.w = f2bf(v.w);
      *(ushort4*)(al + row * 512 + (colb ^ ((row & 7) << 4))) = p;
    }
  }
  __syncthreads();

#pragma unroll 1
  for (int it = 0; it < NTILES; ++it) {
    const long tt = tile0 + it;

    // ---- issue prefetch of next tile (HBM latency hides under compute) ----
    float4 pf[4];
    if (it < NTILES - 1) {
      const float4* src = (const float4*)(x + (tt + 1) * (BM * 256));
#pragma unroll
      for (int i = 0; i < 4; ++i) pf[i] = src[i * 512 + tid];
    }

    // ---- compute from LDS (lgkm only; no vmcnt deps) ----
    f32x4 acc[4];
#pragma unroll
    for (int n = 0; n < 4; ++n) acc[n] = (f32x4){0.f, 0.f, 0.f, 0.f};
#pragma unroll
    for (int kk = 0; kk < 8; ++kk) {
      const int arow = wm * 16 + lr;
      const int colb = (kk * 32 + lhi * 8) * 2;
      short8 a = *(const short8*)(al + arow * 512 + (colb ^ ((arow & 7) << 4)));
#pragma unroll
      for (int n = 0; n < 4; ++n) {
        short8 b = *(const short8*)(bl + ((((wn * 4 + n) * 8 + kk) * 64 + lane) << 4));
        acc[n] = __builtin_amdgcn_mfma_f32_16x16x32_bf16(a, b, acc[n], 0, 0, 0);
      }
    }

    // ---- store this tile (spreads writes over time) ----
    {
      float* orow = out + (tt * BM + wm * 16 + lhi * 4) * 256;
#pragma unroll
      for (int n = 0; n < 4; ++n) {
        const int e = wn * 64 + n * 16 + lr;
#pragma unroll
        for (int r = 0; r < 4; ++r) orow[r * 256 + e] = acc[n][r] + bv[n];
      }
    }

    __syncthreads();   // all waves done reading al
    if (it < NTILES - 1) {
#pragma unroll
      for (int i = 0; i < 4; ++i) {
        int f = i * 512 + tid;
        int row = f >> 6, colb = (f & 63) * 8;
        ushort4 p; p.x = f2bf(pf[i].x); p.y = f2bf(pf[i].y); p.z = f2bf(pf[i].z); p.w = f2bf(pf[i].w);
        *(ushort4*)(al + row * 512 + (colb ^ ((row & 7) << 4))) = p;
      }
    }
    __syncthreads();   // al holds tile it+1
  }
}

extern "C" void kernel_launch(void* const* d_in, const int* in_sizes, int n_in,
                              void* d_out, int out_size, void* d_ws, size_t ws_size,
                              hipStream_t stream) {
  const float* x = (const float*)d_in[0];     // (16, 8192, 256) fp32
  const float* W = (const float*)d_in[1];     // (256, 256) fp32
  const float* b = (const float*)d_in[2];     // (256,) fp32
  float* out = (float*)d_out;                 // (16, 8192, 256) fp32
  unsigned short* Wp = (unsigned short*)d_ws; // 256*256 bf16 = 128 KB

  haar_pack<<<64, 256, 0, stream>>>(W, Wp);

  const int grid = (out_size / 256) / (BM * NTILES);  // 131072 / 512 = 256
  wemb_gemm<<<grid, 512, 0, stream>>>(x, Wp, b, out);
}